// Round 5
// baseline (498.461 us; speedup 1.0000x reference)
//
#include <hip/hip_runtime.h>

// PartialProductAccumulator: 54-step ripple add with dropped carry-out
// == sum of 54 partial products mod 2^108.
// K1: per-bit-column popcount (exact in fp32, max 54), streamed from HBM.
//     1 float4 column/thread, 1728 blocks (27 waves/CU), depth-4 software
//     pipeline. R4 A/B: REGULAR loads (no nontemporal) — the harness's
//     restore-copy leaves the input hot/dirty in L3; nt loads forfeit that.
// K2: in-place per-row 108-bit carry propagation, one thread per row.

#define N_PP   54
#define BITS   108
#define BATCH  16384
#define ROW_F4 (BITS / 4)                    // 27 float4 per row
#define PLANE_F4 ((size_t)BATCH * ROW_F4)    // 442368 float4 per p-plane

typedef float vf4 __attribute__((ext_vector_type(4)));

// ---------------- K1: column counts ----------------
__global__ __launch_bounds__(256)
void count_kernel(const vf4* __restrict__ pps, vf4* __restrict__ cnt) {
    const size_t i0 = (size_t)blockIdx.x * 256 + threadIdx.x;
    const vf4* p = pps + i0;

    vf4 acc = (vf4)(0.f);

    // depth-4 pipeline: 4 loads in flight at all times
    vf4 v0 = p[0 * PLANE_F4];
    vf4 v1 = p[1 * PLANE_F4];
    vf4 v2 = p[2 * PLANE_F4];
    vf4 v3 = p[3 * PLANE_F4];

    // planes 4..51 in groups of 4 (12 iterations)
    for (int q = 4; q + 4 <= N_PP - 2; q += 4) {
        const vf4* pq = p + (size_t)q * PLANE_F4;
        vf4 n0 = pq[0 * PLANE_F4];
        vf4 n1 = pq[1 * PLANE_F4];
        vf4 n2 = pq[2 * PLANE_F4];
        vf4 n3 = pq[3 * PLANE_F4];
        acc += v0; acc += v1; acc += v2; acc += v3;
        v0 = n0; v1 = n1; v2 = n2; v3 = n3;
    }

    // epilogue: planes 52,53 plus the last pipelined group
    vf4 e0 = p[(size_t)(N_PP - 2) * PLANE_F4];
    vf4 e1 = p[(size_t)(N_PP - 1) * PLANE_F4];
    acc += v0; acc += v1; acc += v2; acc += v3;
    acc += e0; acc += e1;

    cnt[i0] = acc;   // stays cache-warm for K2
}

// ---------------- K2: carry propagation ----------------
// One thread per batch row. Row counts -> registers (27 independent float4
// loads), serial carry chain, write back in place (rows disjoint across
// threads; K1->K2 stream-ordered).
__global__ __launch_bounds__(64)
void carry_kernel(vf4* __restrict__ buf) {
    const int row = blockIdx.x * 64 + threadIdx.x;
    vf4* rp = buf + (size_t)row * ROW_F4;

    float r[BITS];
#pragma unroll
    for (int j = 0; j < ROW_F4; ++j) {
        reinterpret_cast<vf4*>(r)[j] = rp[j];
    }

    int c = 0;
#pragma unroll
    for (int i = 0; i < BITS; ++i) {
        const int t = (int)r[i] + c;
        r[i] = (float)(t & 1);
        c = t >> 1;                          // carry out of bit 107 dropped
    }

#pragma unroll
    for (int j = 0; j < ROW_F4; ++j) {
        rp[j] = reinterpret_cast<vf4*>(r)[j];
    }
}

extern "C" void kernel_launch(void* const* d_in, const int* in_sizes, int n_in,
                              void* d_out, int out_size, void* d_ws, size_t ws_size,
                              hipStream_t stream) {
    const vf4* pps = (const vf4*)d_in[0];
    vf4* out = (vf4*)d_out;

    count_kernel<<<(int)(PLANE_F4 / 256), 256, 0, stream>>>(pps, out);
    carry_kernel<<<BATCH / 64, 64, 0, stream>>>(out);
}

// Round 6
// 472.326 us; speedup vs baseline: 1.0553x; 1.0553x over previous
//
#include <hip/hip_runtime.h>

// PartialProductAccumulator: 54-step ripple add with dropped carry-out
// == sum of 54 partial products mod 2^108.
// K1: per-bit-column popcount (exact in fp32, max 54), streamed from HBM.
//     NONTEMPORAL loads (R5 A/B: removing nt cost +29us -- one-pass stream,
//     no L3 reuse; regular loads pollute L2/L3). 2 float4 columns/thread
//     (2 KB contiguous per wave per plane), 864 blocks, 2-plane prefetch
//     pipeline = 8 loads in flight/wave.
// K2: in-place per-row 108-bit carry propagation, one thread per row.

#define N_PP   54
#define BITS   108
#define BATCH  16384
#define ROW_F4 (BITS / 4)                    // 27 float4 per row
#define PLANE_F4 ((size_t)BATCH * ROW_F4)    // 442368 float4 per p-plane

typedef float vf4 __attribute__((ext_vector_type(4)));

// ---------------- K1: column counts ----------------
__global__ __launch_bounds__(256)
void count_kernel(const vf4* __restrict__ pps, vf4* __restrict__ cnt) {
    const size_t base = (size_t)blockIdx.x * 512 + threadIdx.x;
    const vf4* p0 = pps + base;          // column tid
    const vf4* p1 = pps + base + 256;    // column tid+256 (unit-stride insts)

    vf4 a0 = (vf4)(0.f);
    vf4 a1 = (vf4)(0.f);

    // prefetch planes 0 and 1 (4 loads in flight)
    vf4 u0 = __builtin_nontemporal_load(p0);
    vf4 u1 = __builtin_nontemporal_load(p1);
    vf4 w0 = __builtin_nontemporal_load(p0 + PLANE_F4);
    vf4 w1 = __builtin_nontemporal_load(p1 + PLANE_F4);

    // planes 2..53, two per iteration; 8 loads in flight in steady state
    for (int q = 2; q < N_PP; q += 2) {
        const vf4* q0 = p0 + (size_t)q * PLANE_F4;
        const vf4* q1 = p1 + (size_t)q * PLANE_F4;
        vf4 n00 = __builtin_nontemporal_load(q0);
        vf4 n01 = __builtin_nontemporal_load(q1);
        vf4 n10 = __builtin_nontemporal_load(q0 + PLANE_F4);
        vf4 n11 = __builtin_nontemporal_load(q1 + PLANE_F4);
        a0 += u0; a1 += u1;
        a0 += w0; a1 += w1;
        u0 = n00; u1 = n01;
        w0 = n10; w1 = n11;
    }
    a0 += u0; a1 += u1;
    a0 += w0; a1 += w1;

    cnt[base]       = a0;
    cnt[base + 256] = a1;
}

// ---------------- K2: carry propagation ----------------
// One thread per batch row. Row counts -> registers (27 independent float4
// loads), serial carry chain, write back in place (rows disjoint across
// threads; K1->K2 stream-ordered).
__global__ __launch_bounds__(64)
void carry_kernel(vf4* __restrict__ buf) {
    const int row = blockIdx.x * 64 + threadIdx.x;
    vf4* rp = buf + (size_t)row * ROW_F4;

    float r[BITS];
#pragma unroll
    for (int j = 0; j < ROW_F4; ++j) {
        reinterpret_cast<vf4*>(r)[j] = rp[j];
    }

    int c = 0;
#pragma unroll
    for (int i = 0; i < BITS; ++i) {
        const int t = (int)r[i] + c;
        r[i] = (float)(t & 1);
        c = t >> 1;                          // carry out of bit 107 dropped
    }

#pragma unroll
    for (int j = 0; j < ROW_F4; ++j) {
        rp[j] = reinterpret_cast<vf4*>(r)[j];
    }
}

extern "C" void kernel_launch(void* const* d_in, const int* in_sizes, int n_in,
                              void* d_out, int out_size, void* d_ws, size_t ws_size,
                              hipStream_t stream) {
    const vf4* pps = (const vf4*)d_in[0];
    vf4* out = (vf4*)d_out;

    count_kernel<<<(int)(PLANE_F4 / 512), 256, 0, stream>>>(pps, out);
    carry_kernel<<<BATCH / 64, 64, 0, stream>>>(out);
}

// Round 7
// 460.364 us; speedup vs baseline: 1.0828x; 1.0260x over previous
//
#include <hip/hip_runtime.h>

// PartialProductAccumulator: 54-step ripple add with dropped carry-out
// == sum of 54 partial products mod 2^108.
// FUSED single kernel:
//   phase 1: per-bit-column popcount (exact in fp32, max 54), nontemporal
//            streamed from HBM (R5 A/B: removing nt cost +29us), depth-4
//            register pipeline, 1 float4 column per thread.
//   phase 2: counts -> LDS (stride 109, conflict-free), 16 threads/block do
//            the serial 108-step carry (t = cnt + c; bit = t&1; c = t>>1),
//            all 432 threads write the output tile contiguously.
// Block = 432 threads = 16 rows x 27 float4 (rows never straddle blocks);
// 1024 blocks = 4 blocks/CU = 28 waves/CU.

#define N_PP   54
#define BITS   108
#define BATCH  16384
#define ROW_F4 (BITS / 4)                    // 27 float4 per row
#define PLANE_F4 ((size_t)BATCH * ROW_F4)    // 442368 float4 per p-plane
#define ROWS_PB 16                           // batch rows per block
#define TPB     (ROWS_PB * ROW_F4)           // 432 threads (6.75 -> 7 waves)

typedef float vf4 __attribute__((ext_vector_type(4)));

__global__ __launch_bounds__(TPB)
void ppacc_fused(const vf4* __restrict__ pps, vf4* __restrict__ out) {
    __shared__ float counts[ROWS_PB][BITS + 1];   // stride 109 = 13 mod 32

    const int tid = threadIdx.x;
    const size_t i0 = (size_t)blockIdx.x * TPB + tid;
    const vf4* p = pps + i0;

    // ---- phase 1: column popcount, depth-4 nt pipeline ----
    vf4 acc = (vf4)(0.f);

    vf4 v0 = __builtin_nontemporal_load(p + 0 * PLANE_F4);
    vf4 v1 = __builtin_nontemporal_load(p + 1 * PLANE_F4);
    vf4 v2 = __builtin_nontemporal_load(p + 2 * PLANE_F4);
    vf4 v3 = __builtin_nontemporal_load(p + 3 * PLANE_F4);

    for (int q = 4; q + 4 <= N_PP - 2; q += 4) {      // planes 4..51
        const vf4* pq = p + (size_t)q * PLANE_F4;
        vf4 n0 = __builtin_nontemporal_load(pq + 0 * PLANE_F4);
        vf4 n1 = __builtin_nontemporal_load(pq + 1 * PLANE_F4);
        vf4 n2 = __builtin_nontemporal_load(pq + 2 * PLANE_F4);
        vf4 n3 = __builtin_nontemporal_load(pq + 3 * PLANE_F4);
        acc += v0; acc += v1; acc += v2; acc += v3;
        v0 = n0; v1 = n1; v2 = n2; v3 = n3;
    }
    vf4 e0 = __builtin_nontemporal_load(p + (size_t)(N_PP - 2) * PLANE_F4);
    vf4 e1 = __builtin_nontemporal_load(p + (size_t)(N_PP - 1) * PLANE_F4);
    acc += v0; acc += v1; acc += v2; acc += v3;
    acc += e0; acc += e1;

    // ---- phase 2: carry propagation through LDS ----
    {
        const int row = tid / ROW_F4;                 // 0..15
        const int bit = (tid % ROW_F4) * 4;
        counts[row][bit + 0] = acc.x;
        counts[row][bit + 1] = acc.y;
        counts[row][bit + 2] = acc.z;
        counts[row][bit + 3] = acc.w;
    }
    __syncthreads();

    if (tid < ROWS_PB) {
        int c = 0;
#pragma unroll
        for (int i = 0; i < BITS; ++i) {
            const int t = (int)counts[tid][i] + c;
            counts[tid][i] = (float)(t & 1);
            c = t >> 1;                               // carry out of bit 107 dropped
        }
    }
    __syncthreads();

    {
        const int row = tid / ROW_F4;
        const int bit = (tid % ROW_F4) * 4;
        vf4 v;
        v.x = counts[row][bit + 0];
        v.y = counts[row][bit + 1];
        v.z = counts[row][bit + 2];
        v.w = counts[row][bit + 3];
        out[i0] = v;
    }
}

extern "C" void kernel_launch(void* const* d_in, const int* in_sizes, int n_in,
                              void* d_out, int out_size, void* d_ws, size_t ws_size,
                              hipStream_t stream) {
    const vf4* pps = (const vf4*)d_in[0];
    vf4* out = (vf4*)d_out;
    ppacc_fused<<<(int)(PLANE_F4 / TPB), TPB, 0, stream>>>(pps, out);   // 1024 blocks
}